// Round 3
// baseline (768.880 us; speedup 1.0000x reference)
//
#include <hip/hip_runtime.h>

// (B, S, D) = (64, 4096, 256), all float32.
#define B_  64
#define S_  4096
#define D_  256
#define NC  32                               // S-chunks per batch -> 64*32 = 2048 blocks (8/CU)
#define ROWS_PER_CHUNK (S_ / NC)             // 128
#define ROWS_PER_WAVE  (ROWS_PER_CHUNK / 4)  // 32  (4 waves per 256-thr block)
#define ITERS (ROWS_PER_WAVE / 2)            // 16  (2 rows per wave per iteration)

// Workspace layout: [B] int counters | [B*NC] float ws_l | [B*NC*D] float ws_o
#define WS_CNT_OFF  0
#define WS_L_OFF    (B_ * sizeof(int))                      // 256 B
#define WS_O_OFF    (WS_L_OFF + B_ * NC * sizeof(float))    // 256 + 8192 = 8448 (16B-aligned)

// Single fused kernel: streaming scores + weighted accumulation (memory[]
// read exactly once), then the LAST block per batch (device-scope atomic
// counter) reduces the NC chunk-partials and writes the normalized output.
// This removes the second kernel launch entirely.
__global__ __launch_bounds__(256) void attmem_fused(
    const float* __restrict__ aspect,   // [B,1,D]
    const float* __restrict__ memory,   // [B,S,D]
    const float* __restrict__ W,        // [2D,1]
    const float* __restrict__ bias,     // [1]
    int*   __restrict__ cnt,            // [B]     (zeroed by memsetAsync)
    float* __restrict__ ws_l,           // [B,NC]
    float* __restrict__ ws_o,           // [B,NC,D]
    float* __restrict__ out)            // [B,D]
{
    const int chunk = blockIdx.x;
    const int batch = blockIdx.y;
    const int tid   = threadIdx.x;
    const int wave  = tid >> 6;
    const int lane  = tid & 63;
    const int half  = lane >> 5;        // which of the 2 rows this lane serves
    const int hl    = lane & 31;        // lane within the half

    // Per-lane 8-float weight fragment (cols hl*8 .. hl*8+7), register-resident.
    const float4* W4 = (const float4*)W;
    const float4 wm0 = W4[hl * 2 + 0], wm1 = W4[hl * 2 + 1];
    const float4 wa0 = W4[64 + hl * 2 + 0], wa1 = W4[64 + hl * 2 + 1];
    const float4* A4 = (const float4*)(aspect + batch * D_);
    const float4 av0 = A4[hl * 2 + 0], av1 = A4[hl * 2 + 1];

    // a0 = dot(aspect[b], Wa) + bias (wave-redundant, negligible)
    float a0 = av0.x * wa0.x + av0.y * wa0.y + av0.z * wa0.z + av0.w * wa0.w
             + av1.x * wa1.x + av1.y * wa1.y + av1.z * wa1.z + av1.w * wa1.w;
    #pragma unroll
    for (int off = 16; off >= 1; off >>= 1) a0 += __shfl_xor(a0, off, 64);
    a0 += bias[0];

    const float4* mem4 = (const float4*)(memory + (size_t)batch * S_ * D_);
    const int s0 = chunk * ROWS_PER_CHUNK + wave * ROWS_PER_WAVE;

    float  l  = 0.f;
    float4 o0 = make_float4(0.f, 0.f, 0.f, 0.f);
    float4 o1 = make_float4(0.f, 0.f, 0.f, 0.f);

    #pragma unroll 2
    for (int i = 0; i < ITERS; ++i) {
        const int s = s0 + 2 * i + half;
        const size_t base = (size_t)s * (D_ / 4) + hl * 2;
        const float4 x0 = mem4[base + 0];
        const float4 x1 = mem4[base + 1];

        float d = x0.x * wm0.x + x0.y * wm0.y + x0.z * wm0.z + x0.w * wm0.w
                + x1.x * wm1.x + x1.y * wm1.y + x1.z * wm1.z + x1.w * wm1.w;
        // One 5-step shuffle chain reduces BOTH rows (xor within 32-lane half).
        #pragma unroll
        for (int off = 16; off >= 1; off >>= 1) d += __shfl_xor(d, off, 64);

        // g = tanh(d + a0) in (-1,1) -> exp(g) needs no max subtraction.
        const float g  = d + a0;
        const float e2 = __expf(2.f * g);
        const float p  = __expf((e2 - 1.f) / (e2 + 1.f));

        l    += p;
        o0.x += p * x0.x; o0.y += p * x0.y; o0.z += p * x0.z; o0.w += p * x0.w;
        o1.x += p * x1.x; o1.y += p * x1.y; o1.z += p * x1.z; o1.w += p * x1.w;
    }

    // Combine 4 waves x 2 halves through LDS (one-time).
    __shared__ float lds_o[4 * 64 * 8];
    __shared__ float lds_l[8];
    __shared__ int   is_last;
    float4* lo = (float4*)&lds_o[(wave * 64 + lane) * 8];
    lo[0] = o0;
    lo[1] = o1;
    if (hl == 0) lds_l[wave * 2 + half] = l;
    __syncthreads();

    float osum = 0.f;
    #pragma unroll
    for (int w = 0; w < 4; ++w)
        #pragma unroll
        for (int h = 0; h < 2; ++h)
            osum += lds_o[(w * 64 + h * 32 + (tid >> 3)) * 8 + (tid & 7)];
    ws_o[((size_t)batch * NC + chunk) * D_ + tid] = osum;

    if (tid == 0) {
        float ls = 0.f;
        #pragma unroll
        for (int k = 0; k < 8; ++k) ls += lds_l[k];
        ws_l[batch * NC + chunk] = ls;
    }

    // --- last-block-per-batch reduction (replaces pass2) ---
    __threadfence();                    // release: partials visible device-wide
    if (tid == 0) {
        const int prev = atomicAdd(&cnt[batch], 1);   // device scope by default
        is_last = (prev == NC - 1);
    }
    __syncthreads();
    if (!is_last) return;

    __threadfence();                    // acquire: order reads after the atomic
    float lsum = 0.f;
    #pragma unroll
    for (int c = 0; c < NC; ++c) lsum += ws_l[batch * NC + c];

    float od = 0.f;
    #pragma unroll
    for (int c = 0; c < NC; ++c)
        od += ws_o[((size_t)batch * NC + c) * D_ + tid];

    out[batch * D_ + tid] = od / lsum;
}

extern "C" void kernel_launch(void* const* d_in, const int* in_sizes, int n_in,
                              void* d_out, int out_size, void* d_ws, size_t ws_size,
                              hipStream_t stream) {
    const float* aspect = (const float*)d_in[0];
    const float* memory = (const float*)d_in[1];
    const float* W      = (const float*)d_in[2];
    const float* bias   = (const float*)d_in[3];

    int*   cnt  = (int*)((char*)d_ws + WS_CNT_OFF);
    float* ws_l = (float*)((char*)d_ws + WS_L_OFF);
    float* ws_o = (float*)((char*)d_ws + WS_O_OFF);

    // Counters must be zero every call (ws is re-poisoned to 0xAA).
    hipMemsetAsync(cnt, 0, B_ * sizeof(int), stream);

    dim3 grid(NC, B_);
    attmem_fused<<<grid, 256, 0, stream>>>(aspect, memory, W, bias,
                                           cnt, ws_l, ws_o, (float*)d_out);
}

// Round 4
// 360.377 us; speedup vs baseline: 2.1335x; 2.1335x over previous
//
#include <hip/hip_runtime.h>

// (B, S, D) = (64, 4096, 256), all float32.
#define B_  64
#define S_  4096
#define D_  256
#define NC  32                               // S-chunks per batch -> 64*32 = 2048 blocks (8/CU)
#define ROWS_PER_CHUNK (S_ / NC)             // 128
#define ROWS_PER_WAVE  (ROWS_PER_CHUNK / 4)  // 32  (4 waves per 256-thr block)
#define ITERS (ROWS_PER_WAVE / 2)            // 16  (2 rows per wave per iteration)

// Pass 1: fused scores + weighted accumulation, one streaming read of memory[].
// 2 rows per wave per iteration: half = lane>>5 selects the row, lane covers
// 8 contiguous floats. One 5-step xor-shuffle chain reduces BOTH rows' dots.
//
// NOTE (R3 post-mortem): do NOT fuse the cross-block reduction into this
// kernel via atomics + __threadfence(). Device-scope fences per block lower
// to L2 writeback/invalidate on CDNA (per-XCD L2s non-coherent) and collapse
// the streaming pipeline: measured 540 us (vs ~50 us here), VALUBusy 1.9%,
// HBM 250 GB/s. The separate 5 us pass2 launch is far cheaper.
__global__ __launch_bounds__(256) void attmem_pass1(
    const float* __restrict__ aspect,   // [B,1,D]
    const float* __restrict__ memory,   // [B,S,D]
    const float* __restrict__ W,        // [2D,1]
    const float* __restrict__ bias,     // [1]
    float* __restrict__ ws_o,           // [B,NC,D]
    float* __restrict__ ws_l)           // [B,NC]
{
    const int chunk = blockIdx.x;
    const int batch = blockIdx.y;
    const int tid   = threadIdx.x;
    const int wave  = tid >> 6;
    const int lane  = tid & 63;
    const int half  = lane >> 5;        // which of the 2 rows this lane serves
    const int hl    = lane & 31;        // lane within the half

    // Per-lane 8-float weight fragment (cols hl*8 .. hl*8+7), register-resident.
    const float4* W4 = (const float4*)W;
    const float4 wm0 = W4[hl * 2 + 0], wm1 = W4[hl * 2 + 1];
    const float4 wa0 = W4[64 + hl * 2 + 0], wa1 = W4[64 + hl * 2 + 1];
    const float4* A4 = (const float4*)(aspect + batch * D_);
    const float4 av0 = A4[hl * 2 + 0], av1 = A4[hl * 2 + 1];

    // a0 = dot(aspect[b], Wa) + bias (wave-redundant, negligible)
    float a0 = av0.x * wa0.x + av0.y * wa0.y + av0.z * wa0.z + av0.w * wa0.w
             + av1.x * wa1.x + av1.y * wa1.y + av1.z * wa1.z + av1.w * wa1.w;
    #pragma unroll
    for (int off = 16; off >= 1; off >>= 1) a0 += __shfl_xor(a0, off, 64);
    a0 += bias[0];

    const float4* mem4 = (const float4*)(memory + (size_t)batch * S_ * D_);
    const int s0 = chunk * ROWS_PER_CHUNK + wave * ROWS_PER_WAVE;

    float  l  = 0.f;
    float4 o0 = make_float4(0.f, 0.f, 0.f, 0.f);
    float4 o1 = make_float4(0.f, 0.f, 0.f, 0.f);

    #pragma unroll 2
    for (int i = 0; i < ITERS; ++i) {
        const int s = s0 + 2 * i + half;
        const size_t base = (size_t)s * (D_ / 4) + hl * 2;
        const float4 x0 = mem4[base + 0];
        const float4 x1 = mem4[base + 1];

        float d = x0.x * wm0.x + x0.y * wm0.y + x0.z * wm0.z + x0.w * wm0.w
                + x1.x * wm1.x + x1.y * wm1.y + x1.z * wm1.z + x1.w * wm1.w;
        #pragma unroll
        for (int off = 16; off >= 1; off >>= 1) d += __shfl_xor(d, off, 64);

        // g = tanh(d + a0) in (-1,1) -> exp(g) needs no max subtraction.
        const float g  = d + a0;
        const float e2 = __expf(2.f * g);
        const float p  = __expf((e2 - 1.f) / (e2 + 1.f));

        l    += p;
        o0.x += p * x0.x; o0.y += p * x0.y; o0.z += p * x0.z; o0.w += p * x0.w;
        o1.x += p * x1.x; o1.y += p * x1.y; o1.z += p * x1.z; o1.w += p * x1.w;
    }

    // Combine 4 waves x 2 halves through LDS (one-time).
    __shared__ float lds_o[4 * 64 * 8];
    __shared__ float lds_l[8];
    float4* lo = (float4*)&lds_o[(wave * 64 + lane) * 8];
    lo[0] = o0;
    lo[1] = o1;
    if (hl == 0) lds_l[wave * 2 + half] = l;
    __syncthreads();

    // thread t owns output col d=t.
    float osum = 0.f;
    #pragma unroll
    for (int w = 0; w < 4; ++w)
        #pragma unroll
        for (int h = 0; h < 2; ++h)
            osum += lds_o[(w * 64 + h * 32 + (tid >> 3)) * 8 + (tid & 7)];
    ws_o[((size_t)batch * NC + chunk) * D_ + tid] = osum;

    if (tid == 0) {
        float ls = 0.f;
        #pragma unroll
        for (int k = 0; k < 8; ++k) ls += lds_l[k];
        ws_l[batch * NC + chunk] = ls;
    }
}

// Pass 2: reduce NC chunk-partials per batch and normalize. (~2 MB, ~5 us.)
__global__ __launch_bounds__(256) void attmem_pass2(
    const float* __restrict__ ws_o,     // [B,NC,D]
    const float* __restrict__ ws_l,     // [B,NC]
    float* __restrict__ out)            // [B,D]
{
    const int batch = blockIdx.x;
    const int d     = threadIdx.x;

    float lsum = 0.f;
    #pragma unroll
    for (int c = 0; c < NC; ++c) lsum += ws_l[batch * NC + c];

    float osum = 0.f;
    #pragma unroll
    for (int c = 0; c < NC; ++c)
        osum += ws_o[((size_t)batch * NC + c) * D_ + d];

    out[batch * D_ + d] = osum / lsum;
}

extern "C" void kernel_launch(void* const* d_in, const int* in_sizes, int n_in,
                              void* d_out, int out_size, void* d_ws, size_t ws_size,
                              hipStream_t stream) {
    const float* aspect = (const float*)d_in[0];
    const float* memory = (const float*)d_in[1];
    const float* W      = (const float*)d_in[2];
    const float* bias   = (const float*)d_in[3];

    float* ws_o = (float*)d_ws;                    // B*NC*D floats (2 MB)
    float* ws_l = ws_o + (size_t)B_ * NC * D_;     // B*NC floats

    dim3 grid1(NC, B_);
    attmem_pass1<<<grid1, 256, 0, stream>>>(aspect, memory, W, bias, ws_o, ws_l);
    attmem_pass2<<<B_, 256, 0, stream>>>(ws_o, ws_l, (float*)d_out);
}